// Round 2
// baseline (503.983 us; speedup 1.0000x reference)
//
#include <hip/hip_runtime.h>
#include <hip/hip_bf16.h>

// Problem constants
#define B_   2
#define C_   64
#define D_   32
#define H_   96
#define W_   96
#define QK_  32
#define TW_  8
#define HW_  (H_*W_)          // 9216
#define DHW_ (D_*H_*W_)       // 294912
#define TDIM_ 256

// ws layout: floats [0,1024) PB, [1024,2048) KB2 (legacy, unused by attn_main)
// uints  [2048,3072) wqp (32q x 32 c-pairs), [3072,4096) wkp, [4096,6144) wvp (64 x 32)
// floats [6144,7168) PBT[d][q] = bq+tb+pos (transposed), [7168,8192) KBT[d][q]
#define WS_PB   0
#define WS_KB2  1024
#define WS_WQP  2048
#define WS_WKP  3072
#define WS_WVP  4096
#define WS_PBT  6144
#define WS_KBT  7168

typedef __attribute__((ext_vector_type(8))) short short8;
typedef __attribute__((ext_vector_type(4))) float f32x4;

__device__ __forceinline__ uint packbf2(float lo, float hi) {
    uint a = (uint)__bfloat16_as_ushort(__float2bfloat16(lo));
    uint b = (uint)__bfloat16_as_ushort(__float2bfloat16(hi));
    return a | (b << 16);
}

__global__ void prep_kernel(const float* __restrict__ te,
                            const float* __restrict__ wt,
                            const float* __restrict__ bt,
                            const float* __restrict__ bq,
                            const float* __restrict__ bk,
                            const float* __restrict__ wq,
                            const float* __restrict__ wk,
                            const float* __restrict__ wv,
                            const float* __restrict__ pos,
                            float* __restrict__ ws) {
    __shared__ float tm[TDIM_];
    __shared__ float qtb[QK_], ktb[QK_];
    const int t = threadIdx.x;
    float s = 0.f;
    #pragma unroll
    for (int tok = 0; tok < 32; ++tok) s += te[tok*TDIM_ + t];
    tm[t] = s * (1.0f/32.0f);
    __syncthreads();
    if (t < QK_) {
        float acc = bt[t];
        for (int c = 0; c < TDIM_; ++c) acc += wt[t*TDIM_ + c] * tm[c];
        qtb[t] = bq[t] + acc;
        ktb[t] = bk[t] + acc;
    }
    __syncthreads();
    // legacy PB/KB2 (q-major) — harmless
    for (int i = t; i < 1024; i += TDIM_) {
        int q = i >> 5, dd = i & 31;
        ws[WS_PB  + i] = qtb[q] + pos[q*32 + dd];
        ws[WS_KB2 + i] = ktb[q] + pos[q*32 + dd];
    }
    // transposed bias tables PBT[d][q], KBT[d][q] (MFMA acc-init, b128-readable)
    for (int i = t; i < 1024; i += TDIM_) {
        int dd = i >> 5, q = i & 31;
        ws[WS_PBT + i] = qtb[q] + pos[q*32 + dd];
        ws[WS_KBT + i] = ktb[q] + pos[q*32 + dd];
    }
    uint* wsu = reinterpret_cast<uint*>(ws);
    for (int i = t; i < 1024; i += TDIM_) {  // wq: 32 q x 32 c-pairs
        int q = i >> 5, cp = i & 31;
        wsu[WS_WQP + i] = packbf2(wq[q*64 + 2*cp], wq[q*64 + 2*cp + 1]);
    }
    for (int i = t; i < 1024; i += TDIM_) {
        int q = i >> 5, cp = i & 31;
        wsu[WS_WKP + i] = packbf2(wk[q*64 + 2*cp], wk[q*64 + 2*cp + 1]);
    }
    for (int i = t; i < 2048; i += TDIM_) {  // wv: 64 c x 32 c-pairs
        int c = i >> 5, cp = i & 31;
        wsu[WS_WVP + i] = packbf2(wv[c*64 + 2*cp], wv[c*64 + 2*cp + 1]);
    }
}

// Full-MFMA pipeline, TW=8, 256 threads (4 waves), 2304 blocks.
// LDS 80 KiB (dwords), regions with lifetime reuse:
//   R_X  [0,8192):      xs [pos=256][64c bf16] c-fastest, slot^(pos&7) swizzle
//                       -> reused as R_O [pos][64c bf16] slot^(d&7)
//   R_QS [8192,12288):  Q  [pos][32q bf16]  slot^(d&3)   \ reused as
//   R_KS [12288,16384): K  [pos][32q bf16]  slot^(d&3)   / R_V [w][c][32e bf16]
//   R_AP [16384,20480): P  [pos][32e bf16]  slot^(d&3)
// pos = d*8+w. MFMA 16x16x32 bf16 layouts (m89-verified, as round-1):
//   A[m][k]: m=lane&15, k=8*(lane>>4)+i ; B[k][n]: n=lane&15 ; D: n=lane&15, m=4*(lane>>4)+r
__global__ __launch_bounds__(256, 2)
void attn_main(const float* __restrict__ x,
               const float* __restrict__ bv,
               const float* __restrict__ gm,
               const float* __restrict__ ws,
               float* __restrict__ out) {
    __shared__ uint lds[20480];
    uint* const R_X  = lds;
    uint* const R_QS = lds + 8192;
    uint* const R_KS = lds + 12288;
    uint* const R_V  = lds + 8192;
    uint* const R_AP = lds + 16384;
    uint* const R_O  = lds;

    const uint*  wsu = reinterpret_cast<const uint*>(ws);
    const uint*  wqp = wsu + WS_WQP;
    const uint*  wkp = wsu + WS_WKP;
    const uint*  wvp = wsu + WS_WVP;
    const float* PBT = ws + WS_PBT;
    const float* KBT = ws + WS_KBT;

    const int tid  = threadIdx.x;
    const int lane = tid & 63;
    const int wid  = tid >> 6;   // wave 0..3
    const int ln   = lane & 15;
    const int lg   = lane >> 4;
    const int d    = tid >> 3;   // owned depth slice 0..31
    const int w    = tid & 7;    // owned column 0..7

    // block decode (XCD pair swizzle, as round-0): 2304 = 144 G * 16
    const int bx = blockIdx.x;
    const int G  = bx >> 4;
    const int r8 = bx & 7;
    const int sP = (bx >> 3) & 1;
    const int wp_ = G % 6;
    const int hh  = (G / 6) % 12;
    const int b   = G / 72;
    const int h   = hh*8 + r8;
    const int wtile = wp_*2 + sP;

    const int base = b*(C_*DHW_) + d*HW_ + h*W_ + wtile*TW_ + w;

    // ---- Phase 0: load own x column (64 c), pack pairs, write xs row (8x b128) ----
    {
        const int key = tid & 7;
        #pragma unroll
        for (int j = 0; j < 8; ++j) {
            float v0 = x[base + (8*j+0)*DHW_];
            float v1 = x[base + (8*j+1)*DHW_];
            float v2 = x[base + (8*j+2)*DHW_];
            float v3 = x[base + (8*j+3)*DHW_];
            float v4 = x[base + (8*j+4)*DHW_];
            float v5 = x[base + (8*j+5)*DHW_];
            float v6 = x[base + (8*j+6)*DHW_];
            float v7 = x[base + (8*j+7)*DHW_];
            uint4 pk;
            pk.x = packbf2(v0, v1); pk.y = packbf2(v2, v3);
            pk.z = packbf2(v4, v5); pk.w = packbf2(v6, v7);
            *reinterpret_cast<uint4*>(R_X + tid*32 + (((j ^ key) & 7) << 2)) = pk;
        }
    }
    __syncthreads();

    // ---- Phase 1: QK projection GEMM: [wq;wk](64x64c) @ x(64c x 256pos) ----
    {
        uint4 Af[4][2];
        #pragma unroll
        for (int mt = 0; mt < 4; ++mt) {
            const uint* tab = (mt < 2) ? wqp : wkp;
            const int qrow = 16*(mt & 1) + ln;
            #pragma unroll
            for (int kt = 0; kt < 2; ++kt)
                Af[mt][kt] = *reinterpret_cast<const uint4*>(tab + qrow*32 + 16*kt + 4*lg);
        }
        #pragma unroll
        for (int nt = 0; nt < 4; ++nt) {
            const int pos = 16*(4*wid + nt) + ln;
            const int dd  = pos >> 3;           // depth of this column
            short8 Bf[2];
            #pragma unroll
            for (int kt = 0; kt < 2; ++kt) {
                uint4 raw = *reinterpret_cast<const uint4*>(
                    R_X + pos*32 + ((((4*kt + lg) ^ (pos & 7)) & 7) << 2));
                Bf[kt] = __builtin_bit_cast(short8, raw);
            }
            #pragma unroll
            for (int mt = 0; mt < 4; ++mt) {
                const float* bt_ = (mt < 2) ? PBT : KBT;
                f32x4 acc = *reinterpret_cast<const f32x4*>(bt_ + dd*32 + 16*(mt & 1) + 4*lg);
                #pragma unroll
                for (int kt = 0; kt < 2; ++kt)
                    acc = __builtin_amdgcn_mfma_f32_16x16x32_bf16(
                        __builtin_bit_cast(short8, Af[mt][kt]), Bf[kt], acc, 0, 0, 0);
                // rows q = 16*(mt&1)+4*lg+{0..3}: pack two q-pairs, b64 to Qs/Ks
                uint p0 = packbf2(acc[0], acc[1]);
                uint p1 = packbf2(acc[2], acc[3]);
                uint* dst = (mt < 2) ? R_QS : R_KS;
                const int s4  = 2*(mt & 1) + (lg >> 1);
                const int off = (((s4 ^ (dd & 3)) & 3) << 2) + 2*(lg & 1);
                *reinterpret_cast<uint2*>(dst + pos*16 + off) = make_uint2(p0, p1);
            }
        }
    }
    __syncthreads();

    // ---- Phase 2: per-pixel scores (Q^T K), softmax, P -> R_AP ----
    {
        const float rsc = 0.17677669529663687f;  // 1/sqrt(32)
        #pragma unroll
        for (int pp = 0; pp < 2; ++pp) {
            const int wp = 2*wid + pp;           // pixel 0..7
            short8 Aq[2], Bk[2];
            #pragma unroll
            for (int t2 = 0; t2 < 2; ++t2) {
                const int row = (16*t2 + ln)*8 + wp;
                const int off = (((lg ^ (ln & 3)) & 3) << 2);
                uint4 rq = *reinterpret_cast<const uint4*>(R_QS + row*16 + off);
                uint4 rk = *reinterpret_cast<const uint4*>(R_KS + row*16 + off);
                Aq[t2] = __builtin_bit_cast(short8, rq);
                Bk[t2] = __builtin_bit_cast(short8, rk);
            }
            f32x4 sc[2][2];
            #pragma unroll
            for (int mtS = 0; mtS < 2; ++mtS)
                #pragma unroll
                for (int ntS = 0; ntS < 2; ++ntS) {
                    f32x4 z = {0.f, 0.f, 0.f, 0.f};
                    sc[mtS][ntS] = __builtin_amdgcn_mfma_f32_16x16x32_bf16(
                        Aq[mtS], Bk[ntS], z, 0, 0, 0);
                }
            // softmax per row d = 16*mtS + 4*lg + r (reduce over ntS and 16 ln-lanes)
            #pragma unroll
            for (int mtS = 0; mtS < 2; ++mtS) {
                #pragma unroll
                for (int r2 = 0; r2 < 4; ++r2) {
                    float m = fmaxf(sc[mtS][0][r2], sc[mtS][1][r2]);
                    #pragma unroll
                    for (int sh = 1; sh <= 8; sh <<= 1) m = fmaxf(m, __shfl_xor(m, sh));
                    float p0 = __expf((sc[mtS][0][r2] - m) * rsc);
                    float p1 = __expf((sc[mtS][1][r2] - m) * rsc);
                    float sm = p0 + p1;
                    #pragma unroll
                    for (int sh = 1; sh <= 8; sh <<= 1) sm += __shfl_xor(sm, sh);
                    const float rs = 1.0f / sm;
                    p0 *= rs; p1 *= rs;
                    // pack e-pairs across lanes (ln, ln+1), even lanes write
                    const float q0 = __shfl_xor(p0, 1);
                    const float q1 = __shfl_xor(p1, 1);
                    if ((lane & 1) == 0) {
                        const int dd2 = 16*mtS + 4*lg + r2;
                        const int u_  = ln >> 1;
                        const int rowb = (dd2*8 + wp)*16;
                        {   // ntS = 0: logical dword u_
                            const int s3  = (u_ >> 2);
                            const int off = (((s3 ^ (dd2 & 3)) & 3) << 2) + (u_ & 3);
                            R_AP[rowb + off] = packbf2(p0, q0);
                        }
                        {   // ntS = 1: logical dword 8 + u_
                            const int s3  = 2 + (u_ >> 2);
                            const int off = (((s3 ^ (dd2 & 3)) & 3) << 2) + (u_ & 3);
                            R_AP[rowb + off] = packbf2(p1, q1);
                        }
                    }
                }
            }
        }
    }
    __syncthreads();   // Qs/Ks dead; AP visible; R_V may now overwrite R_QS/R_KS

    // ---- Phase 3: V = wv @ x + bv (GEMM over pos), transpose-write to R_V[w][c][e] ----
    {
        short8 Bf[4][2];
        #pragma unroll
        for (int nt = 0; nt < 4; ++nt) {
            const int pos = 16*(4*wid + nt) + ln;
            #pragma unroll
            for (int kt = 0; kt < 2; ++kt) {
                uint4 raw = *reinterpret_cast<const uint4*>(
                    R_X + pos*32 + ((((4*kt + lg) ^ (pos & 7)) & 7) << 2));
                Bf[nt][kt] = __builtin_bit_cast(short8, raw);
            }
        }
        #pragma unroll
        for (int mt = 0; mt < 4; ++mt) {
            short8 Av[2];
            #pragma unroll
            for (int kt = 0; kt < 2; ++kt) {
                uint4 raw = *reinterpret_cast<const uint4*>(wvp + (16*mt + ln)*32 + 16*kt + 4*lg);
                Av[kt] = __builtin_bit_cast(short8, raw);
            }
            const f32x4 bini = *reinterpret_cast<const f32x4*>(bv + 16*mt + 4*lg);
            f32x4 a4[4];
            #pragma unroll
            for (int nt = 0; nt < 4; ++nt) {
                a4[nt] = bini;
                #pragma unroll
                for (int kt = 0; kt < 2; ++kt)
                    a4[nt] = __builtin_amdgcn_mfma_f32_16x16x32_bf16(Av[kt], Bf[nt][kt], a4[nt], 0, 0, 0);
            }
            // lane holds V[c=16mt+4lg+r][pos=16*(4wid+nt)+ln]; e=pos>>3=2T+(ln>>3), w=ln&7.
            // shfl_xor(8) pairs (e=2T, 2T+1); per (r): uint4 over nt = e-run [8wid,8wid+8) for one c.
            #pragma unroll
            for (int r2 = 0; r2 < 4; ++r2) {
                uint u0, u1, u2, u3;
                { float o = a4[0][r2]; float p = __shfl_xor(o, 8); u0 = packbf2(o, p); }
                { float o = a4[1][r2]; float p = __shfl_xor(o, 8); u1 = packbf2(o, p); }
                { float o = a4[2][r2]; float p = __shfl_xor(o, 8); u2 = packbf2(o, p); }
                { float o = a4[3][r2]; float p = __shfl_xor(o, 8); u3 = packbf2(o, p); }
                if ((lane & 8) == 0) {
                    const int c   = 16*mt + 4*lg + r2;
                    const int wv_ = lane & 7;
                    const int phys = (wid ^ lg ^ (wv_ & 3)) & 3;   // key = ((c>>2)&3)^(w&3), (c>>2)&3==lg
                    *reinterpret_cast<uint4*>(R_V + (wv_*64 + c)*16 + (phys << 2)) =
                        make_uint4(u0, u1, u2, u3);
                }
            }
        }
    }
    __syncthreads();   // xs dead (R_X -> R_O); R_V visible

    // ---- Phase 4: per-pixel out2 = V @ P^T (M=c64, N=d32, K=e32); O -> R_O bf16 ----
    {
        #pragma unroll
        for (int pp = 0; pp < 2; ++pp) {
            const int wp = 2*wid + pp;
            short8 Bp[2];
            #pragma unroll
            for (int ntF = 0; ntF < 2; ++ntF) {
                uint4 raw = *reinterpret_cast<const uint4*>(
                    R_AP + ((16*ntF + ln)*8 + wp)*16 + (((lg ^ (ln & 3)) & 3) << 2));
                Bp[ntF] = __builtin_bit_cast(short8, raw);
            }
            #pragma unroll
            for (int mtF = 0; mtF < 4; ++mtF) {
                const int c = 16*mtF + ln;
                const int phys = (lg ^ ((ln >> 2) & 3) ^ (wp & 3)) & 3;
                uint4 raw = *reinterpret_cast<const uint4*>(R_V + (wp*64 + c)*16 + (phys << 2));
                const short8 Avf = __builtin_bit_cast(short8, raw);
                #pragma unroll
                for (int ntF = 0; ntF < 2; ++ntF) {
                    f32x4 z = {0.f, 0.f, 0.f, 0.f};
                    f32x4 oa = __builtin_amdgcn_mfma_f32_16x16x32_bf16(Avf, Bp[ntF], z, 0, 0, 0);
                    // O[c=16mtF+4lg+r][d=16ntF+ln] -> R_O[pos=d*8+wp][c-pairs]
                    const uint p0 = packbf2(oa[0], oa[1]);
                    const uint p1 = packbf2(oa[2], oa[3]);
                    const int dd3 = 16*ntF + ln;
                    const int s4  = 2*mtF + (lg >> 1);
                    const int off = (((s4 ^ (dd3 & 7)) & 7) << 2) + 2*(lg & 1);
                    *reinterpret_cast<uint2*>(R_O + (dd3*8 + wp)*32 + off) = make_uint2(p0, p1);
                }
            }
        }
    }
    __syncthreads();

    // ---- Phase 5: store own column: out = g*O + (1-g)*x (x re-read, L3-hot) ----
    {
        const float gvv = 1.0f / (1.0f + __expf(-gm[0]));
        const float giv = 1.0f - gvv;
        #pragma unroll
        for (int j = 0; j < 8; ++j) {
            uint4 o4 = *reinterpret_cast<const uint4*>(
                R_O + tid*32 + (((j ^ (d & 7)) & 7) << 2));
            const uint us[4] = {o4.x, o4.y, o4.z, o4.w};
            #pragma unroll
            for (int t2 = 0; t2 < 4; ++t2) {
                const uint u = us[t2];
                const int c  = 8*j + 2*t2;
                const int a0 = base + c*DHW_;
                const int a1 = a0 + DHW_;
                const float olo = __uint_as_float(u << 16);
                const float ohi = __uint_as_float(u & 0xffff0000u);
                out[a0] = gvv*olo + giv*x[a0];
                out[a1] = gvv*ohi + giv*x[a1];
            }
        }
    }
}

extern "C" void kernel_launch(void* const* d_in, const int* in_sizes, int n_in,
                              void* d_out, int out_size, void* d_ws, size_t ws_size,
                              hipStream_t stream) {
    const float* x     = (const float*)d_in[0];
    const float* te    = (const float*)d_in[1];
    const float* wq    = (const float*)d_in[2];
    const float* bq    = (const float*)d_in[3];
    const float* wk    = (const float*)d_in[4];
    const float* bk    = (const float*)d_in[5];
    const float* wv    = (const float*)d_in[6];
    const float* bv    = (const float*)d_in[7];
    const float* wt    = (const float*)d_in[8];
    const float* bt    = (const float*)d_in[9];
    const float* pos   = (const float*)d_in[10];
    const float* gamma = (const float*)d_in[11];
    float* out = (float*)d_out;
    float* ws  = (float*)d_ws;

    prep_kernel<<<1, 256, 0, stream>>>(te, wt, bt, bq, bk, wq, wk, wv, pos, ws);

    const int nblk = B_ * H_ * (W_/TW_);   // 2304 = 144 groups * 16
    attn_main<<<nblk, 256, 0, stream>>>(x, bv, gamma, ws, out);
}

// Round 3
// 366.999 us; speedup vs baseline: 1.3733x; 1.3733x over previous
//
#include <hip/hip_runtime.h>
#include <hip/hip_bf16.h>

// Problem constants
#define B_   2
#define C_   64
#define D_   32
#define H_   96
#define W_   96
#define QK_  32
#define TW_  8
#define HW_  (H_*W_)          // 9216
#define DHW_ (D_*H_*W_)       // 294912
#define TDIM_ 256

// ws layout: floats [0,1024) PB, [1024,2048) KB2 (legacy, unused by attn_main)
// uints  [2048,3072) wqp (32q x 32 c-pairs), [3072,4096) wkp, [4096,6144) wvp (64 x 32)
// floats [6144,7168) PBT[d][q] = bq+tb+pos (transposed), [7168,8192) KBT[d][q]
#define WS_PB   0
#define WS_KB2  1024
#define WS_WQP  2048
#define WS_WKP  3072
#define WS_WVP  4096
#define WS_PBT  6144
#define WS_KBT  7168

typedef __attribute__((ext_vector_type(8))) short short8;
typedef __attribute__((ext_vector_type(4))) float f32x4;

__device__ __forceinline__ uint packbf2(float lo, float hi) {
    uint a = (uint)__bfloat16_as_ushort(__float2bfloat16(lo));
    uint b = (uint)__bfloat16_as_ushort(__float2bfloat16(hi));
    return a | (b << 16);
}

__global__ void prep_kernel(const float* __restrict__ te,
                            const float* __restrict__ wt,
                            const float* __restrict__ bt,
                            const float* __restrict__ bq,
                            const float* __restrict__ bk,
                            const float* __restrict__ wq,
                            const float* __restrict__ wk,
                            const float* __restrict__ wv,
                            const float* __restrict__ pos,
                            float* __restrict__ ws) {
    __shared__ float tm[TDIM_];
    __shared__ float qtb[QK_], ktb[QK_];
    const int t = threadIdx.x;
    float s = 0.f;
    #pragma unroll
    for (int tok = 0; tok < 32; ++tok) s += te[tok*TDIM_ + t];
    tm[t] = s * (1.0f/32.0f);
    __syncthreads();
    if (t < QK_) {
        float acc = bt[t];
        for (int c = 0; c < TDIM_; ++c) acc += wt[t*TDIM_ + c] * tm[c];
        qtb[t] = bq[t] + acc;
        ktb[t] = bk[t] + acc;
    }
    __syncthreads();
    // legacy PB/KB2 (q-major) — harmless
    for (int i = t; i < 1024; i += TDIM_) {
        int q = i >> 5, dd = i & 31;
        ws[WS_PB  + i] = qtb[q] + pos[q*32 + dd];
        ws[WS_KB2 + i] = ktb[q] + pos[q*32 + dd];
    }
    // transposed bias tables PBT[d][q], KBT[d][q] (MFMA acc-init, b128-readable)
    for (int i = t; i < 1024; i += TDIM_) {
        int dd = i >> 5, q = i & 31;
        ws[WS_PBT + i] = qtb[q] + pos[q*32 + dd];
        ws[WS_KBT + i] = ktb[q] + pos[q*32 + dd];
    }
    uint* wsu = reinterpret_cast<uint*>(ws);
    for (int i = t; i < 1024; i += TDIM_) {  // wq: 32 q x 32 c-pairs
        int q = i >> 5, cp = i & 31;
        wsu[WS_WQP + i] = packbf2(wq[q*64 + 2*cp], wq[q*64 + 2*cp + 1]);
    }
    for (int i = t; i < 1024; i += TDIM_) {
        int q = i >> 5, cp = i & 31;
        wsu[WS_WKP + i] = packbf2(wk[q*64 + 2*cp], wk[q*64 + 2*cp + 1]);
    }
    for (int i = t; i < 2048; i += TDIM_) {  // wv: 64 c x 32 c-pairs
        int c = i >> 5, cp = i & 31;
        wsu[WS_WVP + i] = packbf2(wv[c*64 + 2*cp], wv[c*64 + 2*cp + 1]);
    }
}

// Full-MFMA pipeline, TW=8, 256 threads (4 waves), 2304 blocks, 2 blocks/CU.
// LDS 80 KiB (dwords), regions with lifetime reuse:
//   R_X  [0,8192):      xs [pos=256][64c bf16] c-fastest, slot^(pos&7) swizzle
//                       -> reused as R_O [pos][64c bf16] slot^(d&7)
//   R_QS [8192,12288):  Q  [pos][32q bf16]  slot^(d&3)   \ reused as
//   R_KS [12288,16384): K  [pos][32q bf16]  slot^(d&3)   / R_V [w][c][32e bf16]
//   R_AP [16384,20480): P  [pos][32e bf16]  slot^(d&3)
// pos = d*8+w. MFMA 16x16x32 bf16 layouts (m89-verified):
//   A[m][k]: m=lane&15, k=8*(lane>>4)+i ; B[k][n]: n=lane&15 ; D: n=lane&15, m=4*(lane>>4)+r
__global__ __launch_bounds__(256, 2)
void attn_main(const float* __restrict__ x,
               const float* __restrict__ bv,
               const float* __restrict__ gm,
               const float* __restrict__ ws,
               float* __restrict__ out) {
    __shared__ uint lds[20480];
    uint* const R_X  = lds;
    uint* const R_QS = lds + 8192;
    uint* const R_KS = lds + 12288;
    uint* const R_V  = lds + 8192;
    uint* const R_AP = lds + 16384;
    uint* const R_O  = lds;

    const uint*  wsu = reinterpret_cast<const uint*>(ws);
    const uint*  wqp = wsu + WS_WQP;
    const uint*  wkp = wsu + WS_WKP;
    const uint*  wvp = wsu + WS_WVP;
    const float* PBT = ws + WS_PBT;
    const float* KBT = ws + WS_KBT;

    const int tid  = threadIdx.x;
    const int lane = tid & 63;
    const int wid  = tid >> 6;   // wave 0..3
    const int ln   = lane & 15;
    const int lg   = lane >> 4;
    const int d    = tid >> 3;   // owned depth slice 0..31
    const int w    = tid & 7;    // owned column 0..7

    // Block decode: quad partners (q2=0..3) cover 4 consecutive wtiles = one full
    // 128B line per (c,d); all 4 share XCD (bx%8==r8) and are dispatch-adjacent.
    // 2304 = 72 G * 32.
    const int bx  = blockIdx.x;
    const int r8  = bx & 7;
    const int q2  = (bx >> 3) & 3;
    const int G   = bx >> 5;            // 0..71
    const int wp_ = G % 3;
    const int hh  = (G / 3) % 12;
    const int b   = G / 36;
    const int h   = hh*8 + r8;
    const int wtile = wp_*4 + q2;       // 0..11

    const int base = b*(C_*DHW_) + d*HW_ + h*W_ + wtile*TW_ + w;

    // ---- Phase 0: batch-load own x column (64 loads in flight), then pack+scatter ----
    uint xp[32];
    {
        float xv[64];
        #pragma unroll
        for (int c = 0; c < 64; ++c) xv[c] = x[base + c*DHW_];
        const int key = tid & 7;
        #pragma unroll
        for (int j = 0; j < 8; ++j) {
            uint4 pk;
            pk.x = packbf2(xv[8*j+0], xv[8*j+1]);
            pk.y = packbf2(xv[8*j+2], xv[8*j+3]);
            pk.z = packbf2(xv[8*j+4], xv[8*j+5]);
            pk.w = packbf2(xv[8*j+6], xv[8*j+7]);
            xp[4*j+0] = pk.x; xp[4*j+1] = pk.y;
            xp[4*j+2] = pk.z; xp[4*j+3] = pk.w;
            *reinterpret_cast<uint4*>(R_X + tid*32 + (((j ^ key) & 7) << 2)) = pk;
        }
    }
    __syncthreads();

    // ---- Phase 1: QK projection GEMM: [wq;wk](64x64c) @ x(64c x 256pos) ----
    {
        uint4 Af[4][2];
        #pragma unroll
        for (int mt = 0; mt < 4; ++mt) {
            const uint* tab = (mt < 2) ? wqp : wkp;
            const int qrow = 16*(mt & 1) + ln;
            #pragma unroll
            for (int kt = 0; kt < 2; ++kt)
                Af[mt][kt] = *reinterpret_cast<const uint4*>(tab + qrow*32 + 16*kt + 4*lg);
        }
        #pragma unroll
        for (int nt = 0; nt < 4; ++nt) {
            const int pos = 16*(4*wid + nt) + ln;
            const int dd  = pos >> 3;           // depth of this column
            short8 Bf[2];
            #pragma unroll
            for (int kt = 0; kt < 2; ++kt) {
                uint4 raw = *reinterpret_cast<const uint4*>(
                    R_X + pos*32 + ((((4*kt + lg) ^ (pos & 7)) & 7) << 2));
                Bf[kt] = __builtin_bit_cast(short8, raw);
            }
            #pragma unroll
            for (int mt = 0; mt < 4; ++mt) {
                const float* bt_ = (mt < 2) ? PBT : KBT;
                f32x4 acc = *reinterpret_cast<const f32x4*>(bt_ + dd*32 + 16*(mt & 1) + 4*lg);
                #pragma unroll
                for (int kt = 0; kt < 2; ++kt)
                    acc = __builtin_amdgcn_mfma_f32_16x16x32_bf16(
                        __builtin_bit_cast(short8, Af[mt][kt]), Bf[kt], acc, 0, 0, 0);
                // rows q = 16*(mt&1)+4*lg+{0..3}: pack two q-pairs, b64 to Qs/Ks
                uint p0 = packbf2(acc[0], acc[1]);
                uint p1 = packbf2(acc[2], acc[3]);
                uint* dst = (mt < 2) ? R_QS : R_KS;
                const int s4  = 2*(mt & 1) + (lg >> 1);
                const int off = (((s4 ^ (dd & 3)) & 3) << 2) + 2*(lg & 1);
                *reinterpret_cast<uint2*>(dst + pos*16 + off) = make_uint2(p0, p1);
            }
        }
    }
    __syncthreads();

    // ---- Phase 2: per-pixel scores (Q^T K), softmax, P -> R_AP ----
    {
        const float rsc = 0.17677669529663687f;  // 1/sqrt(32)
        #pragma unroll
        for (int pp = 0; pp < 2; ++pp) {
            const int wp = 2*wid + pp;           // pixel 0..7
            short8 Aq[2], Bk[2];
            #pragma unroll
            for (int t2 = 0; t2 < 2; ++t2) {
                const int row = (16*t2 + ln)*8 + wp;
                const int off = (((lg ^ (ln & 3)) & 3) << 2);
                uint4 rq = *reinterpret_cast<const uint4*>(R_QS + row*16 + off);
                uint4 rk = *reinterpret_cast<const uint4*>(R_KS + row*16 + off);
                Aq[t2] = __builtin_bit_cast(short8, rq);
                Bk[t2] = __builtin_bit_cast(short8, rk);
            }
            f32x4 sc[2][2];
            #pragma unroll
            for (int mtS = 0; mtS < 2; ++mtS)
                #pragma unroll
                for (int ntS = 0; ntS < 2; ++ntS) {
                    f32x4 z = {0.f, 0.f, 0.f, 0.f};
                    sc[mtS][ntS] = __builtin_amdgcn_mfma_f32_16x16x32_bf16(
                        Aq[mtS], Bk[ntS], z, 0, 0, 0);
                }
            // softmax per row d = 16*mtS + 4*lg + r (reduce over ntS and 16 ln-lanes)
            #pragma unroll
            for (int mtS = 0; mtS < 2; ++mtS) {
                #pragma unroll
                for (int r2 = 0; r2 < 4; ++r2) {
                    float m = fmaxf(sc[mtS][0][r2], sc[mtS][1][r2]);
                    #pragma unroll
                    for (int sh = 1; sh <= 8; sh <<= 1) m = fmaxf(m, __shfl_xor(m, sh));
                    float p0 = __expf((sc[mtS][0][r2] - m) * rsc);
                    float p1 = __expf((sc[mtS][1][r2] - m) * rsc);
                    float sm = p0 + p1;
                    #pragma unroll
                    for (int sh = 1; sh <= 8; sh <<= 1) sm += __shfl_xor(sm, sh);
                    const float rs = 1.0f / sm;
                    p0 *= rs; p1 *= rs;
                    // pack e-pairs across lanes (ln, ln+1), even lanes write
                    const float q0 = __shfl_xor(p0, 1);
                    const float q1 = __shfl_xor(p1, 1);
                    if ((lane & 1) == 0) {
                        const int dd2 = 16*mtS + 4*lg + r2;
                        const int u_  = ln >> 1;
                        const int rowb = (dd2*8 + wp)*16;
                        {   // ntS = 0: logical dword u_
                            const int s3  = (u_ >> 2);
                            const int off = (((s3 ^ (dd2 & 3)) & 3) << 2) + (u_ & 3);
                            R_AP[rowb + off] = packbf2(p0, q0);
                        }
                        {   // ntS = 1: logical dword 8 + u_
                            const int s3  = 2 + (u_ >> 2);
                            const int off = (((s3 ^ (dd2 & 3)) & 3) << 2) + (u_ & 3);
                            R_AP[rowb + off] = packbf2(p1, q1);
                        }
                    }
                }
            }
        }
    }
    __syncthreads();   // Qs/Ks dead; AP visible; R_V may now overwrite R_QS/R_KS

    // ---- Phase 3: V = wv @ x + bv (GEMM over pos), transpose-write to R_V[w][c][e] ----
    {
        short8 Bf[4][2];
        #pragma unroll
        for (int nt = 0; nt < 4; ++nt) {
            const int pos = 16*(4*wid + nt) + ln;
            #pragma unroll
            for (int kt = 0; kt < 2; ++kt) {
                uint4 raw = *reinterpret_cast<const uint4*>(
                    R_X + pos*32 + ((((4*kt + lg) ^ (pos & 7)) & 7) << 2));
                Bf[nt][kt] = __builtin_bit_cast(short8, raw);
            }
        }
        #pragma unroll
        for (int mt = 0; mt < 4; ++mt) {
            short8 Av[2];
            #pragma unroll
            for (int kt = 0; kt < 2; ++kt) {
                uint4 raw = *reinterpret_cast<const uint4*>(wvp + (16*mt + ln)*32 + 16*kt + 4*lg);
                Av[kt] = __builtin_bit_cast(short8, raw);
            }
            const f32x4 bini = *reinterpret_cast<const f32x4*>(bv + 16*mt + 4*lg);
            f32x4 a4[4];
            #pragma unroll
            for (int nt = 0; nt < 4; ++nt) {
                a4[nt] = bini;
                #pragma unroll
                for (int kt = 0; kt < 2; ++kt)
                    a4[nt] = __builtin_amdgcn_mfma_f32_16x16x32_bf16(Av[kt], Bf[nt][kt], a4[nt], 0, 0, 0);
            }
            // lane holds V[c=16mt+4lg+r][pos=16*(4wid+nt)+ln]; e=pos>>3=2T+(ln>>3), w=ln&7.
            // shfl_xor(8) pairs (e=2T, 2T+1); per (r): uint4 over nt = e-run [8wid,8wid+8) for one c.
            #pragma unroll
            for (int r2 = 0; r2 < 4; ++r2) {
                uint u0, u1, u2, u3;
                { float o = a4[0][r2]; float p = __shfl_xor(o, 8); u0 = packbf2(o, p); }
                { float o = a4[1][r2]; float p = __shfl_xor(o, 8); u1 = packbf2(o, p); }
                { float o = a4[2][r2]; float p = __shfl_xor(o, 8); u2 = packbf2(o, p); }
                { float o = a4[3][r2]; float p = __shfl_xor(o, 8); u3 = packbf2(o, p); }
                if ((lane & 8) == 0) {
                    const int c   = 16*mt + 4*lg + r2;
                    const int wv_ = lane & 7;
                    const int phys = (wid ^ lg ^ (wv_ & 3)) & 3;   // key = ((c>>2)&3)^(w&3), (c>>2)&3==lg
                    *reinterpret_cast<uint4*>(R_V + (wv_*64 + c)*16 + (phys << 2)) =
                        make_uint4(u0, u1, u2, u3);
                }
            }
        }
    }
    __syncthreads();   // xs dead (R_X -> R_O); R_V visible

    // ---- Phase 4: per-pixel out2 = V @ P^T (M=c64, N=d32, K=e32); O -> R_O bf16 ----
    {
        #pragma unroll
        for (int pp = 0; pp < 2; ++pp) {
            const int wp = 2*wid + pp;
            short8 Bp[2];
            #pragma unroll
            for (int ntF = 0; ntF < 2; ++ntF) {
                uint4 raw = *reinterpret_cast<const uint4*>(
                    R_AP + ((16*ntF + ln)*8 + wp)*16 + (((lg ^ (ln & 3)) & 3) << 2));
                Bp[ntF] = __builtin_bit_cast(short8, raw);
            }
            #pragma unroll
            for (int mtF = 0; mtF < 4; ++mtF) {
                const int c = 16*mtF + ln;
                const int phys = (lg ^ ((ln >> 2) & 3) ^ (wp & 3)) & 3;
                uint4 raw = *reinterpret_cast<const uint4*>(R_V + (wp*64 + c)*16 + (phys << 2));
                const short8 Avf = __builtin_bit_cast(short8, raw);
                #pragma unroll
                for (int ntF = 0; ntF < 2; ++ntF) {
                    f32x4 z = {0.f, 0.f, 0.f, 0.f};
                    f32x4 oa = __builtin_amdgcn_mfma_f32_16x16x32_bf16(Avf, Bp[ntF], z, 0, 0, 0);
                    // O[c=16mtF+4lg+r][d=16ntF+ln] -> R_O[pos=d*8+wp][c-pairs]
                    const uint p0 = packbf2(oa[0], oa[1]);
                    const uint p1 = packbf2(oa[2], oa[3]);
                    const int dd3 = 16*ntF + ln;
                    const int s4  = 2*mtF + (lg >> 1);
                    const int off = (((s4 ^ (dd3 & 7)) & 7) << 2) + 2*(lg & 1);
                    *reinterpret_cast<uint2*>(R_O + (dd3*8 + wp)*32 + off) = make_uint2(p0, p1);
                }
            }
        }
    }
    __syncthreads();

    // ---- Phase 5: store own column: out = g*O + (1-g)*x (residual from reg xp) ----
    {
        const float gvv = 1.0f / (1.0f + __expf(-gm[0]));
        const float giv = 1.0f - gvv;
        #pragma unroll
        for (int j = 0; j < 8; ++j) {
            uint4 o4 = *reinterpret_cast<const uint4*>(
                R_O + tid*32 + (((j ^ (d & 7)) & 7) << 2));
            const uint os[4] = {o4.x, o4.y, o4.z, o4.w};
            #pragma unroll
            for (int t2 = 0; t2 < 4; ++t2) {
                const uint u  = os[t2];
                const uint xu = xp[4*j + t2];
                const int c   = 8*j + 2*t2;
                const int a0  = base + c*DHW_;
                const float olo = __uint_as_float(u << 16);
                const float ohi = __uint_as_float(u & 0xffff0000u);
                const float xlo = __uint_as_float(xu << 16);
                const float xhi = __uint_as_float(xu & 0xffff0000u);
                out[a0]        = gvv*olo + giv*xlo;
                out[a0 + DHW_] = gvv*ohi + giv*xhi;
            }
        }
    }
}

extern "C" void kernel_launch(void* const* d_in, const int* in_sizes, int n_in,
                              void* d_out, int out_size, void* d_ws, size_t ws_size,
                              hipStream_t stream) {
    const float* x     = (const float*)d_in[0];
    const float* te    = (const float*)d_in[1];
    const float* wq    = (const float*)d_in[2];
    const float* bq    = (const float*)d_in[3];
    const float* wk    = (const float*)d_in[4];
    const float* bk    = (const float*)d_in[5];
    const float* wv    = (const float*)d_in[6];
    const float* bv    = (const float*)d_in[7];
    const float* wt    = (const float*)d_in[8];
    const float* bt    = (const float*)d_in[9];
    const float* pos   = (const float*)d_in[10];
    const float* gamma = (const float*)d_in[11];
    float* out = (float*)d_out;
    float* ws  = (float*)d_ws;

    prep_kernel<<<1, 256, 0, stream>>>(te, wt, bt, bq, bk, wq, wk, wv, pos, ws);

    const int nblk = B_ * H_ * (W_/TW_);   // 2304 = 72 groups * 32
    attn_main<<<nblk, 256, 0, stream>>>(x, bv, gamma, ws, out);
}